// Round 1
// baseline (270.044 us; speedup 1.0000x reference)
//
#include <hip/hip_runtime.h>
#include <stdint.h>

typedef float f4_t __attribute__((ext_vector_type(4)));
typedef __bf16 bf8_t __attribute__((ext_vector_type(8)));
typedef __bf16 bf4_t __attribute__((ext_vector_type(4)));
typedef unsigned short us8_t __attribute__((ext_vector_type(8)));
typedef unsigned short us4_t __attribute__((ext_vector_type(4)));

static __device__ __forceinline__ unsigned short f2bf(float f) {
    union { float f; uint32_t u; } v; v.f = f;
    uint32_t r = v.u + 0x7FFFu + ((v.u >> 16) & 1u);
    return (unsigned short)(r >> 16);
}
static __device__ __forceinline__ float bf2f(unsigned short u) {
    union { uint32_t u; float f; } v; v.u = ((uint32_t)u) << 16;
    return v.f;
}
static __device__ __forceinline__ f4_t mfma16(bf8_t a, bf8_t b, f4_t c) {
    return __builtin_amdgcn_mfma_f32_16x16x32_bf16(a, b, c, 0, 0, 0);
}
static __device__ __forceinline__ float sigf(float x) {
    return 1.0f / (1.0f + __expf(-x));
}

// ---------------- kernel 0: convert inputs to bf16, build q-normalized x ----
__global__ __launch_bounds__(256) void k_convert(
    const float* __restrict__ x, const float* __restrict__ h,
    const float* __restrict__ W1, const float* __restrict__ W2,
    unsigned short* __restrict__ qn, unsigned short* __restrict__ xb,
    unsigned short* __restrict__ hb, unsigned short* __restrict__ w1b,
    unsigned short* __restrict__ w2b)
{
    __shared__ float sred[4];
    int bid = blockIdx.x, t = threadIdx.x;
    if (bid < 256) {
        float v = x[bid * 256 + t];
        float ss = v * v;
        #pragma unroll
        for (int m = 1; m < 64; m <<= 1) ss += __shfl_xor(ss, m, 64);
        if ((t & 63) == 0) sred[t >> 6] = ss;
        __syncthreads();
        float tot = sred[0] + sred[1] + sred[2] + sred[3];
        float rn = 1.0f / fmaxf(sqrtf(tot), 1e-8f);
        xb[bid * 256 + t] = f2bf(v);
        qn[bid * 256 + t] = f2bf(v * rn);
    } else if (bid < 512) {
        int b = bid - 256;
        hb[b * 256 + t] = f2bf(h[b * 256 + t]);
    } else {
        int i0 = (bid - 512) * 256 + t;
        for (int i = i0; i < 1280 * 256; i += 512 * 256) {
            w1b[i] = f2bf(W1[i]);
            w2b[i] = f2bf(W2[i]);
        }
    }
}

// ---------------- kernel 1: preact = x@W1^T + h@W2^T + b1 + b2 --------------
// grid: 80 blocks (4 b-tiles x 20 g-tiles), 256 threads (4 waves)
__global__ __launch_bounds__(256) void k_gates(
    const unsigned short* __restrict__ xb, const unsigned short* __restrict__ hb,
    const unsigned short* __restrict__ w1b, const unsigned short* __restrict__ w2b,
    const float* __restrict__ b1, const float* __restrict__ b2,
    float* __restrict__ pre)
{
    int bb = (blockIdx.x & 3) * 64;
    int gb = (blockIdx.x >> 2) * 64;
    int t = threadIdx.x, w = t >> 6, lane = t & 63;
    int l15 = lane & 15, q8 = (lane >> 4) * 8, q4 = (lane >> 4) * 4;
    int arow = bb + w * 16 + l15;

    f4_t acc[4] = {};
    #pragma unroll
    for (int ks = 0; ks < 8; ++ks) {
        bf8_t a = *(const bf8_t*)&xb[arow * 256 + ks * 32 + q8];
        #pragma unroll
        for (int gc = 0; gc < 4; ++gc) {
            bf8_t bf = *(const bf8_t*)&w1b[(gb + gc * 16 + l15) * 256 + ks * 32 + q8];
            acc[gc] = mfma16(a, bf, acc[gc]);
        }
    }
    #pragma unroll
    for (int ks = 0; ks < 8; ++ks) {
        bf8_t a = *(const bf8_t*)&hb[arow * 256 + ks * 32 + q8];
        #pragma unroll
        for (int gc = 0; gc < 4; ++gc) {
            bf8_t bf = *(const bf8_t*)&w2b[(gb + gc * 16 + l15) * 256 + ks * 32 + q8];
            acc[gc] = mfma16(a, bf, acc[gc]);
        }
    }
    #pragma unroll
    for (int gc = 0; gc < 4; ++gc) {
        int g = gb + gc * 16 + l15;
        float bias = b1[g] + b2[g];
        #pragma unroll
        for (int r = 0; r < 4; ++r) {
            int b = bb + w * 16 + q4 + r;
            pre[b * 1280 + g] = acc[gc][r] + bias;
        }
    }
}

// ---------------- kernel 2: DND memory partials (flash-style, fixed shift) --
// grid: NBLK=256 blocks x 512 threads (8 waves). Each block owns an L-chunk.
__global__ __launch_bounds__(512, 2) void k_dnd(
    const float* __restrict__ keys, const float* __restrict__ vals,
    const unsigned short* __restrict__ qn,
    unsigned short* __restrict__ opart, float* __restrict__ dpart,
    int L, int chunk)
{
    __shared__ unsigned short Kl[64 * 256];   // [l][d] bf16, swizzled
    __shared__ unsigned short Vl[256 * 64];   // [h][l] bf16 (transposed), swizzled
    __shared__ unsigned short Pl[256 * 64];   // [b][l] bf16, swizzled
    __shared__ float rno[64];

    const int t = threadIdx.x;
    const int w = t >> 6, lane = t & 63;
    const int l15 = lane & 15;
    const int q8 = (lane >> 4) * 8, q4 = (lane >> 4) * 4;
    const int blk = blockIdx.x;
    const int base = blk * chunk;
    int nkeys = L - base;
    if (nkeys > chunk) nkeys = chunk;
    if (nkeys < 0) nkeys = 0;
    const int nt = (nkeys + 63) >> 6;

    // preload Q fragments (rows 32w..32w+31, bf16, from global; L2-resident)
    bf8_t qa[2][8];
    #pragma unroll
    for (int bt = 0; bt < 2; ++bt)
        #pragma unroll
        for (int ks = 0; ks < 8; ++ks)
            qa[bt][ks] = *(const bf8_t*)&qn[(w * 32 + bt * 16 + l15) * 256 + ks * 32 + q8];

    f4_t o[2][16] = {};
    float den[2][4] = {};

    for (int tt = 0; tt < nt; ++tt) {
        // ---- stage K tile (64 x 256) + per-key rnorm ----
        {
            int rowi = t >> 5, lane31 = t & 31;
            int d0 = lane31 * 8;
            #pragma unroll
            for (int it = 0; it < 4; ++it) {
                int lrow = it * 16 + rowi;
                int loff = tt * 64 + lrow;
                bool valid = loff < nkeys;
                f4_t a = {0.f, 0.f, 0.f, 0.f}, b = {0.f, 0.f, 0.f, 0.f};
                if (valid) {
                    const float* src = keys + (size_t)(base + loff) * 256 + d0;
                    a = *(const f4_t*)src;
                    b = *(const f4_t*)(src + 4);
                }
                float ss = a[0]*a[0] + a[1]*a[1] + a[2]*a[2] + a[3]*a[3]
                         + b[0]*b[0] + b[1]*b[1] + b[2]*b[2] + b[3]*b[3];
                #pragma unroll
                for (int m = 1; m < 32; m <<= 1) ss += __shfl_xor(ss, m, 64);
                us8_t uv;
                uv[0] = f2bf(a[0]); uv[1] = f2bf(a[1]); uv[2] = f2bf(a[2]); uv[3] = f2bf(a[3]);
                uv[4] = f2bf(b[0]); uv[5] = f2bf(b[1]); uv[6] = f2bf(b[2]); uv[7] = f2bf(b[3]);
                int idx = lrow * 256 + (d0 ^ ((lrow & 7) << 3));
                *(us8_t*)&Kl[idx] = uv;
                if (lane31 == 0)
                    rno[lrow] = valid ? (1.0f / fmaxf(sqrtf(ss), 1e-8f)) : 0.0f;
            }
        }
        // ---- stage V tile transposed: Vl[h][l] ----
        {
            int hh = t & 255;
            int lgrp = (t >> 8) * 4;
            #pragma unroll
            for (int it = 0; it < 8; ++it) {
                int l0 = it * 8 + lgrp;
                us4_t uv;
                #pragma unroll
                for (int r = 0; r < 4; ++r) {
                    int loff = tt * 64 + l0 + r;
                    float vv = (loff < nkeys) ? vals[(size_t)(base + loff) * 256 + hh] : 0.0f;
                    uv[r] = f2bf(vv);
                }
                int idx = hh * 64 + (l0 ^ ((hh & 15) << 2));
                *(us4_t*)&Vl[idx] = uv;
            }
        }
        __syncthreads();

        // ---- GEMM1: S = Q @ K^T (per wave: 32 b-rows x 64 l-cols) ----
        f4_t s[2][4] = {};
        #pragma unroll
        for (int lc = 0; lc < 4; ++lc) {
            int l = lc * 16 + l15;
            int sw = (l & 7) << 3;
            #pragma unroll
            for (int ks = 0; ks < 8; ++ks) {
                bf8_t kf = *(const bf8_t*)&Kl[l * 256 + ((ks * 32 + q8) ^ sw)];
                s[0][lc] = mfma16(qa[0][ks], kf, s[0][lc]);
                s[1][lc] = mfma16(qa[1][ks], kf, s[1][lc]);
            }
        }

        // ---- p = exp(s*rnorm - 1), den accum, write P to LDS ----
        #pragma unroll
        for (int lc = 0; lc < 4; ++lc) {
            int l = lc * 16 + l15;
            float rn = rno[l];
            bool valid = (tt * 64 + l) < nkeys;
            #pragma unroll
            for (int bt = 0; bt < 2; ++bt) {
                #pragma unroll
                for (int r = 0; r < 4; ++r) {
                    float p = valid ? __expf(s[bt][lc][r] * rn - 1.0f) : 0.0f;
                    den[bt][r] += p;
                    int bl = w * 32 + bt * 16 + q4 + r;
                    Pl[bl * 64 + (l ^ ((bl & 7) << 3))] = f2bf(p);
                }
            }
        }

        // Each wave reads only its own 32 P-rows -> no barrier needed here.
        // ---- GEMM2: O += P @ V ----
        bf8_t pa[2][2];
        #pragma unroll
        for (int bt = 0; bt < 2; ++bt) {
            int brow = w * 32 + bt * 16 + l15;
            int sw = (brow & 7) << 3;
            pa[bt][0] = *(const bf8_t*)&Pl[brow * 64 + (q8 ^ sw)];
            pa[bt][1] = *(const bf8_t*)&Pl[brow * 64 + ((32 + q8) ^ sw)];
        }
        #pragma unroll
        for (int hc = 0; hc < 16; ++hc) {
            int hrow = hc * 16 + l15;
            int sw = (hrow & 15) << 2;
            union { bf8_t v8; bf4_t v4[2]; } vf0, vf1;
            vf0.v4[0] = *(const bf4_t*)&Vl[hrow * 64 + ((q8) ^ sw)];
            vf0.v4[1] = *(const bf4_t*)&Vl[hrow * 64 + ((q8 + 4) ^ sw)];
            vf1.v4[0] = *(const bf4_t*)&Vl[hrow * 64 + ((32 + q8) ^ sw)];
            vf1.v4[1] = *(const bf4_t*)&Vl[hrow * 64 + ((32 + q8 + 4) ^ sw)];
            #pragma unroll
            for (int bt = 0; bt < 2; ++bt) {
                o[bt][hc] = mfma16(pa[bt][0], vf0.v8, o[bt][hc]);
                o[bt][hc] = mfma16(pa[bt][1], vf1.v8, o[bt][hc]);
            }
        }
        __syncthreads();
    }

    // ---- write bf16 partial num and fp32 partial den ----
    #pragma unroll
    for (int bt = 0; bt < 2; ++bt) {
        #pragma unroll
        for (int hc = 0; hc < 16; ++hc) {
            #pragma unroll
            for (int r = 0; r < 4; ++r) {
                int b = w * 32 + bt * 16 + q4 + r;
                int hcol = hc * 16 + l15;
                opart[((size_t)blk * 256 + b) * 256 + hcol] = f2bf(o[bt][hc][r]);
            }
        }
    }
    #pragma unroll
    for (int bt = 0; bt < 2; ++bt) {
        #pragma unroll
        for (int r = 0; r < 4; ++r) {
            float d = den[bt][r];
            #pragma unroll
            for (int m = 1; m < 16; m <<= 1) d += __shfl_xor(d, m, 64);
            if (l15 == 0)
                dpart[blk * 256 + (w * 32 + bt * 16 + q4 + r)] = d;
        }
    }
}

// ---------------- kernel 3: reduce partials + LSTM epilogue -----------------
// grid: 256 blocks (one per batch row) x 256 threads (one per h)
__global__ __launch_bounds__(256) void k_reduce(
    const unsigned short* __restrict__ opart, const float* __restrict__ dpart,
    const float* __restrict__ pre, const float* __restrict__ c_in,
    float* __restrict__ out)
{
    __shared__ float sred[4];
    int b = blockIdx.x, t = threadIdx.x;

    float ds = dpart[t * 256 + b];
    #pragma unroll
    for (int m = 1; m < 64; m <<= 1) ds += __shfl_xor(ds, m, 64);
    if ((t & 63) == 0) sred[t >> 6] = ds;
    __syncthreads();
    float dtot = sred[0] + sred[1] + sred[2] + sred[3];
    dtot = fmaxf(dtot, 1e-30f);

    float num = 0.0f;
    #pragma unroll 8
    for (int k = 0; k < 256; ++k)
        num += bf2f(opart[(size_t)k * 65536 + b * 256 + t]);

    float m = tanhf(num / dtot);
    const float* p = pre + b * 1280;
    float fg = sigf(p[t]);
    float ig = sigf(p[256 + t]);
    float og = sigf(p[512 + t]);
    float rg = sigf(p[768 + t]);
    float cn = tanhf(p[1024 + t]);
    float co = c_in[b * 256 + t];
    float ct = fg * co + ig * cn + rg * m;
    float ht = og * tanhf(ct);
    out[b * 256 + t] = ht;
    out[65536 + b * 256 + t] = ct;
}

// ---------------- launch ----------------------------------------------------
extern "C" void kernel_launch(void* const* d_in, const int* in_sizes, int n_in,
                              void* d_out, int out_size, void* d_ws, size_t ws_size,
                              hipStream_t stream)
{
    const float* x    = (const float*)d_in[0];
    const float* h    = (const float*)d_in[1];
    const float* c    = (const float*)d_in[2];
    const float* W1   = (const float*)d_in[3];
    const float* b1   = (const float*)d_in[4];
    const float* W2   = (const float*)d_in[5];
    const float* b2   = (const float*)d_in[6];
    const float* keys = (const float*)d_in[7];
    const float* vals = (const float*)d_in[8];
    int L = in_sizes[7] / 256;

    char* ws = (char*)d_ws;
    unsigned short* qn    = (unsigned short*)(ws + 0);
    unsigned short* xb    = (unsigned short*)(ws + 131072);
    unsigned short* hb    = (unsigned short*)(ws + 262144);
    unsigned short* w1b   = (unsigned short*)(ws + 393216);
    unsigned short* w2b   = (unsigned short*)(ws + 1048576);
    float*          pre   = (float*)(ws + 1703936);
    float*          dpart = (float*)(ws + 3014656);
    unsigned short* opart = (unsigned short*)(ws + 3276800);

    int chunk = (L + 255) / 256;

    k_convert<<<dim3(1024), dim3(256), 0, stream>>>(x, h, W1, W2, qn, xb, hb, w1b, w2b);
    k_gates<<<dim3(80), dim3(256), 0, stream>>>(xb, hb, w1b, w2b, b1, b2, pre);
    k_dnd<<<dim3(256), dim3(512), 0, stream>>>(keys, vals, qn, opart, dpart, L, chunk);
    k_reduce<<<dim3(256), dim3(256), 0, stream>>>(opart, dpart, pre, c, (float*)d_out);

    (void)n_in; (void)out_size; (void)ws_size;
}

// Round 2
// 253.248 us; speedup vs baseline: 1.0663x; 1.0663x over previous
//
#include <hip/hip_runtime.h>
#include <stdint.h>

typedef float f4_t __attribute__((ext_vector_type(4)));
typedef __bf16 bf8_t __attribute__((ext_vector_type(8)));
typedef __bf16 bf4_t __attribute__((ext_vector_type(4)));
typedef unsigned short us8_t __attribute__((ext_vector_type(8)));
typedef unsigned short us4_t __attribute__((ext_vector_type(4)));

static __device__ __forceinline__ unsigned short f2bf(float f) {
    union { float f; uint32_t u; } v; v.f = f;
    uint32_t r = v.u + 0x7FFFu + ((v.u >> 16) & 1u);
    return (unsigned short)(r >> 16);
}
static __device__ __forceinline__ float bf2f(unsigned short u) {
    union { uint32_t u; float f; } v; v.u = ((uint32_t)u) << 16;
    return v.f;
}
static __device__ __forceinline__ f4_t mfma16(bf8_t a, bf8_t b, f4_t c) {
    return __builtin_amdgcn_mfma_f32_16x16x32_bf16(a, b, c, 0, 0, 0);
}
static __device__ __forceinline__ float sigf(float x) {
    return 1.0f / (1.0f + __expf(-x));
}

// ---------------- kernel 0: convert inputs to bf16, build q-normalized x ----
__global__ __launch_bounds__(256) void k_convert(
    const float* __restrict__ x, const float* __restrict__ h,
    const float* __restrict__ W1, const float* __restrict__ W2,
    unsigned short* __restrict__ qn, unsigned short* __restrict__ xb,
    unsigned short* __restrict__ hb, unsigned short* __restrict__ w1b,
    unsigned short* __restrict__ w2b)
{
    __shared__ float sred[4];
    int bid = blockIdx.x, t = threadIdx.x;
    if (bid < 256) {
        float v = x[bid * 256 + t];
        float ss = v * v;
        #pragma unroll
        for (int m = 1; m < 64; m <<= 1) ss += __shfl_xor(ss, m, 64);
        if ((t & 63) == 0) sred[t >> 6] = ss;
        __syncthreads();
        float tot = sred[0] + sred[1] + sred[2] + sred[3];
        float rn = 1.0f / fmaxf(sqrtf(tot), 1e-8f);
        xb[bid * 256 + t] = f2bf(v);
        qn[bid * 256 + t] = f2bf(v * rn);
    } else if (bid < 512) {
        int b = bid - 256;
        hb[b * 256 + t] = f2bf(h[b * 256 + t]);
    } else {
        int i0 = (bid - 512) * 256 + t;
        for (int i = i0; i < 1280 * 256; i += 512 * 256) {
            w1b[i] = f2bf(W1[i]);
            w2b[i] = f2bf(W2[i]);
        }
    }
}

// ---------------- kernel 1: preact = x@W1^T + h@W2^T + b1 + b2 --------------
__global__ __launch_bounds__(256) void k_gates(
    const unsigned short* __restrict__ xb, const unsigned short* __restrict__ hb,
    const unsigned short* __restrict__ w1b, const unsigned short* __restrict__ w2b,
    const float* __restrict__ b1, const float* __restrict__ b2,
    float* __restrict__ pre)
{
    int bb = (blockIdx.x & 3) * 64;
    int gb = (blockIdx.x >> 2) * 64;
    int t = threadIdx.x, w = t >> 6, lane = t & 63;
    int l15 = lane & 15, q8 = (lane >> 4) * 8, q4 = (lane >> 4) * 4;
    int arow = bb + w * 16 + l15;

    f4_t acc[4] = {};
    #pragma unroll
    for (int ks = 0; ks < 8; ++ks) {
        bf8_t a = *(const bf8_t*)&xb[arow * 256 + ks * 32 + q8];
        #pragma unroll
        for (int gc = 0; gc < 4; ++gc) {
            bf8_t bf = *(const bf8_t*)&w1b[(gb + gc * 16 + l15) * 256 + ks * 32 + q8];
            acc[gc] = mfma16(a, bf, acc[gc]);
        }
    }
    #pragma unroll
    for (int ks = 0; ks < 8; ++ks) {
        bf8_t a = *(const bf8_t*)&hb[arow * 256 + ks * 32 + q8];
        #pragma unroll
        for (int gc = 0; gc < 4; ++gc) {
            bf8_t bf = *(const bf8_t*)&w2b[(gb + gc * 16 + l15) * 256 + ks * 32 + q8];
            acc[gc] = mfma16(a, bf, acc[gc]);
        }
    }
    #pragma unroll
    for (int gc = 0; gc < 4; ++gc) {
        int g = gb + gc * 16 + l15;
        float bias = b1[g] + b2[g];
        #pragma unroll
        for (int r = 0; r < 4; ++r) {
            int b = bb + w * 16 + q4 + r;
            pre[b * 1280 + g] = acc[gc][r] + bias;
        }
    }
}

// ---------------- kernel 2: DND memory partials (pipelined, h-split) --------
// grid: 512 blocks = 256 L-chunks x 2 h-halves. Twin h-halves of a chunk are
// mapped to the same XCD (bid and bid+8) so K is twin-served from L2.
// 512 threads (8 waves). Wave w owns b-rows 32w..32w+31 (2x16). Each block
// computes o[256 b][128 h-half] partial over its L-chunk.
__global__ __launch_bounds__(512, 2) void k_dnd(
    const float* __restrict__ keys, const float* __restrict__ vals,
    const unsigned short* __restrict__ qn,
    unsigned short* __restrict__ opart, float* __restrict__ dpart,
    int L, int chunk)
{
    __shared__ __align__(16) char smem[81920];
    unsigned short* Kl = (unsigned short*)smem;            // [64][256] normalized bf16, swz 16B x row&7
    unsigned short* Vl = (unsigned short*)(smem + 65536 - 32768); // [128 h][64 l] bf16, swz 8B x h&15
    unsigned short* Pl = (unsigned short*)(smem + 49152);  // [256 b][64 l] bf16, swz 16B x b&7

    const int t = threadIdx.x;
    const int w = t >> 6;
    const int lane = t & 63;
    const int l15 = lane & 15;
    const int q8 = (lane >> 4) * 8;
    const int q4 = (lane >> 4) * 4;

    const int bid = blockIdx.x;
    const int hhalf = (bid >> 3) & 1;
    const int lchunk = (bid & 7) | ((bid >> 4) << 3);
    const int base = lchunk * chunk;
    int nkeys = L - base;
    if (nkeys > chunk) nkeys = chunk;
    if (nkeys < 0) nkeys = 0;
    const int nt = (nkeys + 63) >> 6;

    // staging thread mappings
    const int krow = t >> 5;            // 0..15 (row group for K)
    const int kd0  = (t & 31) * 8;      // float col, 32 lanes x 8 floats = 256
    const int vh0  = (t & 31) * 4;      // h within half: 0..124
    const int vl0  = (t >> 5) * 4;      // l: 0..60

    // resident Q fragments (qn is L2-resident bf16)
    bf8_t qa[2][8];
    #pragma unroll
    for (int bt = 0; bt < 2; ++bt)
        #pragma unroll
        for (int ks = 0; ks < 8; ++ks)
            qa[bt][ks] = *(const bf8_t*)&qn[(w * 32 + bt * 16 + l15) * 256 + ks * 32 + q8];

    f4_t o[2][8] = {};
    float den[2][4] = {};
    f4_t kst[4][2], vst[4];

    auto issue = [&](int tt) {
        #pragma unroll
        for (int it = 0; it < 4; ++it) {
            int row = tt * 64 + it * 16 + krow;
            if (row < nkeys) {
                const float* src = keys + (size_t)(base + row) * 256 + kd0;
                kst[it][0] = *(const f4_t*)src;
                kst[it][1] = *(const f4_t*)(src + 4);
            } else {
                kst[it][0] = f4_t{0.f, 0.f, 0.f, 0.f};
                kst[it][1] = f4_t{0.f, 0.f, 0.f, 0.f};
            }
        }
        #pragma unroll
        for (int r = 0; r < 4; ++r) {
            int row = tt * 64 + vl0 + r;
            if (row < nkeys)
                vst[r] = *(const f4_t*)&vals[(size_t)(base + row) * 256 + hhalf * 128 + vh0];
            else
                vst[r] = f4_t{0.f, 0.f, 0.f, 0.f};
        }
    };

    issue(0);

    for (int tt = 0; tt < nt; ++tt) {
        // Full barrier: all waves done reading LDS tile tt-1. The implied
        // vmcnt(0) drain only waits on tile-tt loads, needed immediately below.
        __syncthreads();

        // ---- convert K: normalize row, bf16, swizzled store ----
        #pragma unroll
        for (int it = 0; it < 4; ++it) {
            f4_t a = kst[it][0], b = kst[it][1];
            float ss = a[0]*a[0] + a[1]*a[1] + a[2]*a[2] + a[3]*a[3]
                     + b[0]*b[0] + b[1]*b[1] + b[2]*b[2] + b[3]*b[3];
            #pragma unroll
            for (int m = 1; m < 32; m <<= 1) ss += __shfl_xor(ss, m, 64);
            float rn = 1.0f / fmaxf(sqrtf(ss), 1e-8f);
            int lrow = it * 16 + krow;
            us8_t uv;
            uv[0] = f2bf(a[0]*rn); uv[1] = f2bf(a[1]*rn);
            uv[2] = f2bf(a[2]*rn); uv[3] = f2bf(a[3]*rn);
            uv[4] = f2bf(b[0]*rn); uv[5] = f2bf(b[1]*rn);
            uv[6] = f2bf(b[2]*rn); uv[7] = f2bf(b[3]*rn);
            *(us8_t*)&Kl[lrow * 256 + (kd0 ^ ((lrow & 7) << 3))] = uv;
        }
        // ---- convert V: 4x4 in-register transpose, store [h][l] ----
        #pragma unroll
        for (int j = 0; j < 4; ++j) {
            int hh = vh0 + j;
            us4_t uv;
            uv[0] = f2bf(vst[0][j]); uv[1] = f2bf(vst[1][j]);
            uv[2] = f2bf(vst[2][j]); uv[3] = f2bf(vst[3][j]);
            *(us4_t*)&Vl[hh * 64 + (vl0 ^ ((hh & 15) << 2))] = uv;
        }

        // prefetch next tile -> registers; stays in flight through the GEMMs
        if (tt + 1 < nt) issue(tt + 1);

        // LDS-ready barrier WITHOUT vmcnt drain (raw barrier + lgkm only)
        asm volatile("s_waitcnt lgkmcnt(0)" ::: "memory");
        __builtin_amdgcn_s_barrier();

        // ---- GEMM1: S = Q @ Kn^T ----
        f4_t s[2][4] = {};
        #pragma unroll
        for (int lc = 0; lc < 4; ++lc) {
            int l = lc * 16 + l15;
            int sw = (l & 7) << 3;
            #pragma unroll
            for (int ks = 0; ks < 8; ++ks) {
                bf8_t kf = *(const bf8_t*)&Kl[l * 256 + ((ks * 32 + q8) ^ sw)];
                s[0][lc] = mfma16(qa[0][ks], kf, s[0][lc]);
                s[1][lc] = mfma16(qa[1][ks], kf, s[1][lc]);
            }
        }

        // ---- p = exp(s - 1) (sims in [-1,1] -> fixed shift), write P ----
        #pragma unroll
        for (int lc = 0; lc < 4; ++lc) {
            int l = lc * 16 + l15;
            bool valid = (tt * 64 + l) < nkeys;
            #pragma unroll
            for (int bt = 0; bt < 2; ++bt) {
                #pragma unroll
                for (int r = 0; r < 4; ++r) {
                    float p = valid ? __expf(s[bt][lc][r] - 1.0f) : 0.0f;
                    den[bt][r] += p;
                    int bl = w * 32 + bt * 16 + q4 + r;
                    Pl[bl * 64 + (l ^ ((bl & 7) << 3))] = f2bf(p);
                }
            }
        }

        // ---- GEMM2: O += P @ V (wave reads only its own P rows) ----
        bf8_t pa[2][2];
        #pragma unroll
        for (int bt = 0; bt < 2; ++bt) {
            int brow = w * 32 + bt * 16 + l15;
            int sw = (brow & 7) << 3;
            pa[bt][0] = *(const bf8_t*)&Pl[brow * 64 + (q8 ^ sw)];
            pa[bt][1] = *(const bf8_t*)&Pl[brow * 64 + ((32 + q8) ^ sw)];
        }
        #pragma unroll
        for (int hc = 0; hc < 8; ++hc) {
            int hrow = hc * 16 + l15;
            int sw = (hrow & 15) << 2;
            union { bf8_t v8; bf4_t v4[2]; } vf0, vf1;
            vf0.v4[0] = *(const bf4_t*)&Vl[hrow * 64 + ((q8) ^ sw)];
            vf0.v4[1] = *(const bf4_t*)&Vl[hrow * 64 + ((q8 + 4) ^ sw)];
            vf1.v4[0] = *(const bf4_t*)&Vl[hrow * 64 + ((32 + q8) ^ sw)];
            vf1.v4[1] = *(const bf4_t*)&Vl[hrow * 64 + ((32 + q8 + 4) ^ sw)];
            #pragma unroll
            for (int bt = 0; bt < 2; ++bt) {
                o[bt][hc] = mfma16(pa[bt][0], vf0.v8, o[bt][hc]);
                o[bt][hc] = mfma16(pa[bt][1], vf1.v8, o[bt][hc]);
            }
        }
    }

    // ---- epilogue: LDS transpose -> fully coalesced 16B/lane stores ----
    __syncthreads();
    unsigned short* Ol = (unsigned short*)smem;   // [256 b][128 h]
    #pragma unroll
    for (int bt = 0; bt < 2; ++bt)
        #pragma unroll
        for (int hc = 0; hc < 8; ++hc)
            #pragma unroll
            for (int r = 0; r < 4; ++r)
                Ol[(w * 32 + bt * 16 + q4 + r) * 128 + hc * 16 + l15] = f2bf(o[bt][hc][r]);
    __syncthreads();
    {
        size_t obase = (size_t)(lchunk * 2 + hhalf) * 32768;
        #pragma unroll
        for (int it = 0; it < 8; ++it) {
            int off = it * 4096 + t * 8;
            *(us8_t*)&opart[obase + off] = *(const us8_t*)&Ol[off];
        }
    }
    if (hhalf == 0) {
        #pragma unroll
        for (int bt = 0; bt < 2; ++bt)
            #pragma unroll
            for (int r = 0; r < 4; ++r) {
                float d = den[bt][r];
                #pragma unroll
                for (int m = 1; m < 16; m <<= 1) d += __shfl_xor(d, m, 64);
                if (l15 == 0)
                    dpart[lchunk * 256 + w * 32 + bt * 16 + q4 + r] = d;
            }
    }
}

// ---------------- kernel 3: reduce partials + LSTM epilogue -----------------
// grid: 256 blocks (one per batch row) x 512 threads
__global__ __launch_bounds__(512) void k_reduce(
    const unsigned short* __restrict__ opart, const float* __restrict__ dpart,
    const float* __restrict__ pre, const float* __restrict__ c_in,
    float* __restrict__ out)
{
    __shared__ float part[256];
    __shared__ float sred[8];
    int b = blockIdx.x, t = threadIdx.x;

    float ds = (t < 256) ? dpart[t * 256 + b] : 0.0f;
    #pragma unroll
    for (int m = 1; m < 64; m <<= 1) ds += __shfl_xor(ds, m, 64);
    if ((t & 63) == 0) sred[t >> 6] = ds;

    int hcol = t & 255;
    int seg = t >> 8;                     // 0 or 1: which half of the lc range
    int hh = hcol >> 7;
    size_t stridebase = (size_t)hh * 32768 + (size_t)b * 128 + (hcol & 127);

    float n0 = 0.f, n1 = 0.f, n2 = 0.f, n3 = 0.f;
    for (int lc = seg * 128; lc < seg * 128 + 128; lc += 4) {
        n0 += bf2f(opart[(size_t)(lc + 0) * 65536 + stridebase]);
        n1 += bf2f(opart[(size_t)(lc + 1) * 65536 + stridebase]);
        n2 += bf2f(opart[(size_t)(lc + 2) * 65536 + stridebase]);
        n3 += bf2f(opart[(size_t)(lc + 3) * 65536 + stridebase]);
    }
    float num = (n0 + n1) + (n2 + n3);
    if (seg == 1) part[hcol] = num;
    __syncthreads();
    if (seg == 0) {
        num += part[hcol];
        float dtot = sred[0] + sred[1] + sred[2] + sred[3]
                   + sred[4] + sred[5] + sred[6] + sred[7];
        dtot = fmaxf(dtot, 1e-30f);

        float m = tanhf(num / dtot);
        const float* p = pre + b * 1280;
        float fg = sigf(p[hcol]);
        float ig = sigf(p[256 + hcol]);
        float og = sigf(p[512 + hcol]);
        float rg = sigf(p[768 + hcol]);
        float cn = tanhf(p[1024 + hcol]);
        float co = c_in[b * 256 + hcol];
        float ct = fg * co + ig * cn + rg * m;
        float ht = og * tanhf(ct);
        out[b * 256 + hcol] = ht;
        out[65536 + b * 256 + hcol] = ct;
    }
}

// ---------------- launch ----------------------------------------------------
extern "C" void kernel_launch(void* const* d_in, const int* in_sizes, int n_in,
                              void* d_out, int out_size, void* d_ws, size_t ws_size,
                              hipStream_t stream)
{
    const float* x    = (const float*)d_in[0];
    const float* h    = (const float*)d_in[1];
    const float* c    = (const float*)d_in[2];
    const float* W1   = (const float*)d_in[3];
    const float* b1   = (const float*)d_in[4];
    const float* W2   = (const float*)d_in[5];
    const float* b2   = (const float*)d_in[6];
    const float* keys = (const float*)d_in[7];
    const float* vals = (const float*)d_in[8];
    int L = in_sizes[7] / 256;

    char* ws = (char*)d_ws;
    unsigned short* qn    = (unsigned short*)(ws + 0);
    unsigned short* xb    = (unsigned short*)(ws + 131072);
    unsigned short* hb    = (unsigned short*)(ws + 262144);
    unsigned short* w1b   = (unsigned short*)(ws + 393216);
    unsigned short* w2b   = (unsigned short*)(ws + 1048576);
    float*          pre   = (float*)(ws + 1703936);
    float*          dpart = (float*)(ws + 3014656);
    unsigned short* opart = (unsigned short*)(ws + 3276800);

    int chunk = (L + 255) / 256;

    k_convert<<<dim3(1024), dim3(256), 0, stream>>>(x, h, W1, W2, qn, xb, hb, w1b, w2b);
    k_gates<<<dim3(80), dim3(256), 0, stream>>>(xb, hb, w1b, w2b, b1, b2, pre);
    k_dnd<<<dim3(512), dim3(512), 0, stream>>>(keys, vals, qn, opart, dpart, L, chunk);
    k_reduce<<<dim3(256), dim3(512), 0, stream>>>(opart, dpart, pre, c, (float*)d_out);

    (void)n_in; (void)out_size; (void)ws_size;
}

// Round 3
// 110.508 us; speedup vs baseline: 2.4437x; 2.2917x over previous
//
#include <hip/hip_runtime.h>
#include <stdint.h>

typedef float f4_t __attribute__((ext_vector_type(4)));
typedef __bf16 bf8_t __attribute__((ext_vector_type(8)));
typedef unsigned short us4_t __attribute__((ext_vector_type(4)));
typedef unsigned short us8_t __attribute__((ext_vector_type(8)));

static __device__ __forceinline__ unsigned short f2bf(float f) {
    union { float f; uint32_t u; } v; v.f = f;
    uint32_t r = v.u + 0x7FFFu + ((v.u >> 16) & 1u);
    return (unsigned short)(r >> 16);
}
static __device__ __forceinline__ float bf2f(unsigned short u) {
    union { uint32_t u; float f; } v; v.u = ((uint32_t)u) << 16;
    return v.f;
}
static __device__ __forceinline__ f4_t mfma16(bf8_t a, bf8_t b, f4_t c) {
    return __builtin_amdgcn_mfma_f32_16x16x32_bf16(a, b, c, 0, 0, 0);
}
static __device__ __forceinline__ float sigf(float x) {
    return 1.0f / (1.0f + __expf(-x));
}
static __device__ __forceinline__ void gload_lds16(const void* g, void* l) {
    __builtin_amdgcn_global_load_lds(
        (const __attribute__((address_space(1))) void*)g,
        (__attribute__((address_space(3))) void*)l, 16, 0, 0);
}

// ---------------- kernel 0: convert x/h/W to bf16, build q-normalized x ----
__global__ __launch_bounds__(256) void k_convert(
    const float* __restrict__ x, const float* __restrict__ h,
    const float* __restrict__ W1, const float* __restrict__ W2,
    unsigned short* __restrict__ qn, unsigned short* __restrict__ xb,
    unsigned short* __restrict__ hb, unsigned short* __restrict__ w1b,
    unsigned short* __restrict__ w2b)
{
    __shared__ float sred[4];
    int bid = blockIdx.x, t = threadIdx.x;
    if (bid < 256) {
        float v = x[bid * 256 + t];
        float ss = v * v;
        #pragma unroll
        for (int m = 1; m < 64; m <<= 1) ss += __shfl_xor(ss, m, 64);
        if ((t & 63) == 0) sred[t >> 6] = ss;
        __syncthreads();
        float tot = sred[0] + sred[1] + sred[2] + sred[3];
        float rn = 1.0f / fmaxf(sqrtf(tot), 1e-8f);
        xb[bid * 256 + t] = f2bf(v);
        qn[bid * 256 + t] = f2bf(v * rn);
    } else if (bid < 512) {
        int b = bid - 256;
        hb[b * 256 + t] = f2bf(h[b * 256 + t]);
    } else {
        int i0 = (bid - 512) * 256 + t;
        for (int i = i0; i < 1280 * 256; i += 512 * 256) {
            w1b[i] = f2bf(W1[i]);
            w2b[i] = f2bf(W2[i]);
        }
    }
}

// ---------------- kernel 1: preact = x@W1^T + h@W2^T + b1 + b2 --------------
__global__ __launch_bounds__(256) void k_gates(
    const unsigned short* __restrict__ xb, const unsigned short* __restrict__ hb,
    const unsigned short* __restrict__ w1b, const unsigned short* __restrict__ w2b,
    const float* __restrict__ b1, const float* __restrict__ b2,
    float* __restrict__ pre)
{
    int bb = (blockIdx.x & 3) * 64;
    int gb = (blockIdx.x >> 2) * 64;
    int t = threadIdx.x, w = t >> 6, lane = t & 63;
    int l15 = lane & 15, q8 = (lane >> 4) * 8, q4 = (lane >> 4) * 4;
    int arow = bb + w * 16 + l15;

    f4_t acc[4] = {};
    #pragma unroll
    for (int ks = 0; ks < 8; ++ks) {
        bf8_t a = *(const bf8_t*)&xb[arow * 256 + ks * 32 + q8];
        #pragma unroll
        for (int gc = 0; gc < 4; ++gc) {
            bf8_t bf = *(const bf8_t*)&w1b[(gb + gc * 16 + l15) * 256 + ks * 32 + q8];
            acc[gc] = mfma16(a, bf, acc[gc]);
        }
    }
    #pragma unroll
    for (int ks = 0; ks < 8; ++ks) {
        bf8_t a = *(const bf8_t*)&hb[arow * 256 + ks * 32 + q8];
        #pragma unroll
        for (int gc = 0; gc < 4; ++gc) {
            bf8_t bf = *(const bf8_t*)&w2b[(gb + gc * 16 + l15) * 256 + ks * 32 + q8];
            acc[gc] = mfma16(a, bf, acc[gc]);
        }
    }
    #pragma unroll
    for (int gc = 0; gc < 4; ++gc) {
        int g = gb + gc * 16 + l15;
        float bias = b1[g] + b2[g];
        #pragma unroll
        for (int r = 0; r < 4; ++r) {
            int b = bb + w * 16 + q4 + r;
            pre[b * 1280 + g] = acc[gc][r] + bias;
        }
    }
}

// ---------------- kernel P: keys -> normalized bf16, pre-swizzled tiles -----
// Output layout: kn[tile][ri][c] element at tile*16384 + ri*256 + (c ^ ((ri&7)<<3))
// == the exact LDS image k_dnd wants, so global_load_lds is a linear copy.
__global__ __launch_bounds__(256) void k_prep(
    const float* __restrict__ keys, unsigned short* __restrict__ kn, int L)
{
    int tile = blockIdx.x;
    int t = threadIdx.x;
    int w4 = t >> 6;            // 0..3 (wave)
    int lane = t & 63;
    int c0 = lane * 4;
    #pragma unroll 4
    for (int it = 0; it < 16; ++it) {
        int ri = it * 4 + w4;
        int grow = tile * 64 + ri;
        us4_t uv = {0, 0, 0, 0};
        if (grow < L) {
            f4_t v = *(const f4_t*)&keys[(size_t)grow * 256 + c0];
            float ss = v[0]*v[0] + v[1]*v[1] + v[2]*v[2] + v[3]*v[3];
            #pragma unroll
            for (int m = 1; m < 64; m <<= 1) ss += __shfl_xor(ss, m, 64);
            float rn = 1.0f / fmaxf(sqrtf(ss), 1e-8f);
            uv[0] = f2bf(v[0]*rn); uv[1] = f2bf(v[1]*rn);
            uv[2] = f2bf(v[2]*rn); uv[3] = f2bf(v[3]*rn);
        }
        *(us4_t*)&kn[(size_t)tile * 16384 + ri * 256 + (c0 ^ ((ri & 7) << 3))] = uv;
    }
}

// ---------------- kernel 2: DND memory partials ------------------------------
// 256 blocks = 128 chunks x 2 b-halves (twins bid/bid+8 -> same XCD, share
// kn/vals via L2). 512 threads (8 waves); wave w owns b-rows w*16..w*16+15.
// K staged via async global_load_lds (double-buffered, counted vmcnt);
// V staged via register f4 prefetch + in-reg transpose -> LDS [h][l].
__global__ __launch_bounds__(512, 2) void k_dnd(
    const float* __restrict__ vals, const unsigned short* __restrict__ kn,
    const unsigned short* __restrict__ qn,
    unsigned short* __restrict__ opart, float* __restrict__ dpart,
    int L, int CH, int TILES)
{
    // LDS: Kbuf0 @0 (32KB) | Kbuf1 @32768 | Vl @65536 (32KB) | Pl @98304 (16KB)
    __shared__ __align__(16) char smem[114688];
    unsigned short* Vl = (unsigned short*)(smem + 65536);
    unsigned short* Pl = (unsigned short*)(smem + 98304);

    const int t = threadIdx.x;
    const int w = t >> 6;
    const int lane = t & 63;
    const int l15 = lane & 15;
    const int q8 = (lane >> 4) * 8;
    const int q4 = (lane >> 4) * 4;

    const int bid = blockIdx.x;
    const int bhalf = (bid >> 3) & 1;
    const int chunk = (bid & 7) | ((bid >> 4) << 3);
    const int base = chunk * CH;
    int nkeys = L - base;
    if (nkeys > CH) nkeys = CH;
    if (nkeys < 0) nkeys = 0;
    const int nt = (nkeys + 63) >> 6;

    // V staging map: wave w covers l-rows w*8..w*8+7; lane covers h = 4*lane..+3
    const int h4 = lane * 4;

    // Q fragments: wave's 16 b-rows (A-frag row = l15)
    bf8_t qa[8];
    #pragma unroll
    for (int ks = 0; ks < 8; ++ks)
        qa[ks] = *(const bf8_t*)&qn[(bhalf * 128 + w * 16 + l15) * 256 + ks * 32 + q8];

    f4_t o[16] = {};
    float den[4] = {};
    f4_t vst[8];

    if (nt > 0) {
        // prologue: issue K(0) -> buf0, V(0) -> regs
        {
            size_t koff = (size_t)(chunk * TILES) * 32768;
            #pragma unroll
            for (int c = 0; c < 4; ++c)
                gload_lds16((const char*)kn + koff + c * 8192 + w * 1024 + lane * 16,
                            smem + c * 8192 + w * 1024);
            #pragma unroll
            for (int r = 0; r < 8; ++r) {
                int row = base + w * 8 + r;
                row = min(row, L - 1);
                vst[r] = *(const f4_t*)&vals[(size_t)row * 256 + h4];
            }
        }

        for (int tt = 0; tt < nt; ++tt) {
            const int cur = tt & 1;
            // 1. issue K(t+1) -> other buffer (async; 4 x 1KB per wave)
            {
                int tn = tt + 1 < nt ? tt + 1 : nt - 1;
                size_t koff = (size_t)(chunk * TILES + tn) * 32768;
                char* kb = smem + (cur ^ 1) * 32768;
                #pragma unroll
                for (int c = 0; c < 4; ++c)
                    gload_lds16((const char*)kn + koff + c * 8192 + w * 1024 + lane * 16,
                                kb + c * 8192 + w * 1024);
            }
            // 2. wait: K(t) in LDS + V(t) in regs (leave K(t+1)'s 4 in flight)
            asm volatile("s_waitcnt vmcnt(4)" ::: "memory");
            // 3. convert V(t): in-reg 8x4 transpose -> Vl[h][l] (swizzled)
            #pragma unroll
            for (int j = 0; j < 4; ++j) {
                int hh = h4 + j;
                us8_t uv;
                #pragma unroll
                for (int r = 0; r < 8; ++r) uv[r] = f2bf(vst[r][j]);
                *(us8_t*)&Vl[hh * 64 + ((w * 8) ^ ((hh & 7) << 3))] = uv;
            }
            // 4. issue V(t+1) -> regs
            {
                int tn = tt + 1 < nt ? tt + 1 : nt - 1;
                #pragma unroll
                for (int r = 0; r < 8; ++r) {
                    int row = base + tn * 64 + w * 8 + r;
                    row = min(row, L - 1);
                    vst[r] = *(const f4_t*)&vals[(size_t)row * 256 + h4];
                }
            }
            // 5. LDS-ready barrier (no vmcnt drain: K(t+1)/V(t+1) stay in flight)
            asm volatile("s_waitcnt lgkmcnt(0)\n\ts_barrier" ::: "memory");
            __builtin_amdgcn_sched_barrier(0);

            // 6. GEMM1: S = Q @ Kn^T (wave: 16 b x 64 l)
            const unsigned short* Kl = (const unsigned short*)(smem + cur * 32768);
            f4_t s[4] = {};
            __builtin_amdgcn_s_setprio(1);
            #pragma unroll
            for (int lc = 0; lc < 4; ++lc) {
                int l = lc * 16 + l15;
                int sw = (l & 7) << 3;
                #pragma unroll
                for (int ks = 0; ks < 8; ++ks) {
                    bf8_t kf = *(const bf8_t*)&Kl[l * 256 + ((ks * 32 + q8) ^ sw)];
                    s[lc] = mfma16(qa[ks], kf, s[lc]);
                }
            }
            __builtin_amdgcn_s_setprio(0);

            // 7. p = exp(s - 1) (sims in [-1,1]); accumulate den; P -> LDS
            #pragma unroll
            for (int lc = 0; lc < 4; ++lc) {
                int l = lc * 16 + l15;
                bool valid = (tt * 64 + l) < nkeys;
                #pragma unroll
                for (int r = 0; r < 4; ++r) {
                    float p = valid ? __expf(s[lc][r] - 1.0f) : 0.0f;
                    den[r] += p;
                    int br = w * 16 + q4 + r;
                    Pl[br * 64 + (l ^ ((br & 7) << 3))] = f2bf(p);
                }
            }

            // 8. GEMM2: O += P @ V (wave reads only its own P rows)
            {
                int brow = w * 16 + l15;
                int swp = (brow & 7) << 3;
                bf8_t pa0 = *(const bf8_t*)&Pl[brow * 64 + (q8 ^ swp)];
                bf8_t pa1 = *(const bf8_t*)&Pl[brow * 64 + ((32 + q8) ^ swp)];
                __builtin_amdgcn_s_setprio(1);
                #pragma unroll
                for (int hc = 0; hc < 16; ++hc) {
                    int hh = hc * 16 + l15;
                    int swv = (hh & 7) << 3;
                    bf8_t vf0 = *(const bf8_t*)&Vl[hh * 64 + (q8 ^ swv)];
                    bf8_t vf1 = *(const bf8_t*)&Vl[hh * 64 + ((32 + q8) ^ swv)];
                    o[hc] = mfma16(pa0, vf0, o[hc]);
                    o[hc] = mfma16(pa1, vf1, o[hc]);
                }
                __builtin_amdgcn_s_setprio(0);
            }

            // 9. end-of-iter barrier (protects Kbuf[cur] + Vl for next iter)
            asm volatile("s_waitcnt lgkmcnt(0)\n\ts_barrier" ::: "memory");
        }
    }

    // ---- epilogue: drain async loads, LDS transpose, coalesced stores ----
    asm volatile("s_waitcnt vmcnt(0)" ::: "memory");
    __syncthreads();
    unsigned short* Ol = (unsigned short*)smem;   // [128 b][256 h]
    #pragma unroll
    for (int hc = 0; hc < 16; ++hc)
        #pragma unroll
        for (int r = 0; r < 4; ++r)
            Ol[(w * 16 + q4 + r) * 256 + hc * 16 + l15] = f2bf(o[hc][r]);
    __syncthreads();
    {
        size_t ob = (size_t)(chunk * 2 + bhalf) * 32768;
        #pragma unroll
        for (int it = 0; it < 8; ++it) {
            int off = it * 4096 + t * 8;
            *(us8_t*)&opart[ob + off] = *(const us8_t*)&Ol[off];
        }
    }
    #pragma unroll
    for (int r = 0; r < 4; ++r) {
        float d = den[r];
        #pragma unroll
        for (int m = 1; m < 16; m <<= 1) d += __shfl_xor(d, m, 64);
        if (l15 == 0)
            dpart[chunk * 256 + bhalf * 128 + w * 16 + q4 + r] = d;
    }
}

// ---------------- kernel 3: reduce partials + LSTM epilogue -----------------
__global__ __launch_bounds__(256) void k_reduce(
    const unsigned short* __restrict__ opart, const float* __restrict__ dpart,
    const float* __restrict__ pre, const float* __restrict__ c_in,
    float* __restrict__ out)
{
    __shared__ float sred[4];
    int b = blockIdx.x, t = threadIdx.x;

    float ds = (t < 128) ? dpart[t * 256 + b] : 0.0f;
    #pragma unroll
    for (int m = 1; m < 64; m <<= 1) ds += __shfl_xor(ds, m, 64);
    if ((t & 63) == 0) sred[t >> 6] = ds;
    __syncthreads();
    float dtot = fmaxf(sred[0] + sred[1] + sred[2] + sred[3], 1e-30f);

    int bh = b >> 7, br = b & 127;
    float n0 = 0.f, n1 = 0.f, n2 = 0.f, n3 = 0.f;
    for (int ck = 0; ck < 128; ck += 4) {
        n0 += bf2f(opart[(size_t)((ck + 0) * 2 + bh) * 32768 + br * 256 + t]);
        n1 += bf2f(opart[(size_t)((ck + 1) * 2 + bh) * 32768 + br * 256 + t]);
        n2 += bf2f(opart[(size_t)((ck + 2) * 2 + bh) * 32768 + br * 256 + t]);
        n3 += bf2f(opart[(size_t)((ck + 3) * 2 + bh) * 32768 + br * 256 + t]);
    }
    float num = (n0 + n1) + (n2 + n3);

    float m = tanhf(num / dtot);
    const float* p = pre + b * 1280;
    float fg = sigf(p[t]);
    float ig = sigf(p[256 + t]);
    float og = sigf(p[512 + t]);
    float rg = sigf(p[768 + t]);
    float cn = tanhf(p[1024 + t]);
    float co = c_in[b * 256 + t];
    float ct = fg * co + ig * cn + rg * m;
    float ht = og * tanhf(ct);
    out[b * 256 + t] = ht;
    out[65536 + b * 256 + t] = ct;
}

// ---------------- launch ----------------------------------------------------
extern "C" void kernel_launch(void* const* d_in, const int* in_sizes, int n_in,
                              void* d_out, int out_size, void* d_ws, size_t ws_size,
                              hipStream_t stream)
{
    const float* x    = (const float*)d_in[0];
    const float* h    = (const float*)d_in[1];
    const float* c    = (const float*)d_in[2];
    const float* W1   = (const float*)d_in[3];
    const float* b1   = (const float*)d_in[4];
    const float* W2   = (const float*)d_in[5];
    const float* b2   = (const float*)d_in[6];
    const float* keys = (const float*)d_in[7];
    const float* vals = (const float*)d_in[8];
    int L = in_sizes[7] / 256;

    // chunk geometry: 128 chunks, each a multiple of 64 keys
    int TILES = (L + 128 * 64 - 1) / (128 * 64);   // tiles per chunk
    int CH = TILES * 64;                           // keys per chunk

    char* ws = (char*)d_ws;
    unsigned short* qn    = (unsigned short*)(ws + 0);
    unsigned short* xb    = (unsigned short*)(ws + 131072);
    unsigned short* hb    = (unsigned short*)(ws + 262144);
    unsigned short* w1b   = (unsigned short*)(ws + 393216);
    unsigned short* w2b   = (unsigned short*)(ws + 1048576);
    float*          pre   = (float*)(ws + 1703936);
    float*          dpart = (float*)(ws + 3014656);
    unsigned short* kn    = (unsigned short*)(ws + 3145728);
    unsigned short* opart = (unsigned short*)(ws + 3145728 + (size_t)128 * TILES * 32768);

    k_convert<<<dim3(1024), dim3(256), 0, stream>>>(x, h, W1, W2, qn, xb, hb, w1b, w2b);
    k_gates<<<dim3(80), dim3(256), 0, stream>>>(xb, hb, w1b, w2b, b1, b2, pre);
    k_prep<<<dim3(128 * TILES), dim3(256), 0, stream>>>(keys, kn, L);
    k_dnd<<<dim3(256), dim3(512), 0, stream>>>(vals, kn, qn, opart, dpart, L, CH, TILES);
    k_reduce<<<dim3(256), dim3(256), 0, stream>>>(opart, dpart, pre, c, (float*)d_out);

    (void)n_in; (void)out_size; (void)ws_size;
}